// Round 1
// baseline (250.389 us; speedup 1.0000x reference)
//
#include <hip/hip_runtime.h>
#include <hip/hip_bf16.h>
#include <hip/hip_fp16.h>

// Edge-MLP: score[e] = W3·relu(W2·relu(W1u·h[src[e]] + W1v·h[dst[e]] + b1) + b2) + b3
// Strategy: f16 MFMA (fp32 accumulate), fused single kernel, 64-edge tiles.

#define N_NODES 100000
#define N_EDGES 500000
#define F       128            // IN_FEATS
#define HID     128
#define TE      64             // edges per tile
#define NT      ((N_EDGES + TE - 1) / TE)   // 7813 tiles
#define GRID    512
#define BLOCK   512            // 8 waves

typedef _Float16 f16x8 __attribute__((ext_vector_type(8)));
typedef float    f32x4 __attribute__((ext_vector_type(4)));

__global__ __launch_bounds__(BLOCK) void edge_mlp_kernel(
    const float* __restrict__ h,
    const int*   __restrict__ src,
    const int*   __restrict__ dst,
    const float* __restrict__ W1,   // [128][256] row-major
    const float* __restrict__ b1,   // [128]
    const float* __restrict__ W2,   // [128][128]
    const float* __restrict__ b2,   // [128]
    const float* __restrict__ W3,   // [1][128]
    const float* __restrict__ b3,   // [1]
    float*       __restrict__ out)  // [500000]
{
    // A tile: [64 edges][256 k] f16, XOR-swizzled (byte ^= (edge&7)<<4). 32 KB.
    __shared__ __align__(128) char Alds[TE * 256 * 2];
    // X tile: [64 edges][128 cols] f16, swizzled. Used for X1, then reused for X2. 16 KB.
    __shared__ __align__(128) char Xlds[TE * 128 * 2];

    const int tid  = threadIdx.x;
    const int wave = tid >> 6;        // 0..7
    const int lane = tid & 63;
    const int l15  = lane & 15;
    const int lk   = lane >> 4;       // 0..3 (k-group)

    // ---- per-block weight fragment preload (f32 -> f16 regs) ----
    // wave w owns output columns n = w*16 + (lane&15) for BOTH layers.
    const int n1 = wave * 16 + l15;

    f16x8 w1f[8];                     // B-frag: B[k][n] = W1[n][k], k = kt*32 + lk*8 + j
    #pragma unroll
    for (int kt = 0; kt < 8; ++kt) {
        const float* p = W1 + n1 * 256 + kt * 32 + lk * 8;
        f16x8 v;
        #pragma unroll
        for (int j = 0; j < 8; ++j) v[j] = (_Float16)p[j];
        w1f[kt] = v;
    }
    const float b1v = b1[n1];

    f16x8 w2f[4];                     // B[k][n] = W2[n][k]
    #pragma unroll
    for (int kt = 0; kt < 4; ++kt) {
        const float* p = W2 + n1 * 128 + kt * 32 + lk * 8;
        f16x8 v;
        #pragma unroll
        for (int j = 0; j < 8; ++j) v[j] = (_Float16)p[j];
        w2f[kt] = v;
    }
    const float b2v = b2[n1];

    float w3r[16];                    // score stage: thread t uses cols (t&7)*16 .. +15
    {
        const float* p = W3 + (tid & 7) * 16;
        #pragma unroll
        for (int i = 0; i < 16; ++i) w3r[i] = p[i];
    }
    const float b3v = b3[0];

    // gather decomposition: 4 threads per node-vector (128 floats), 128 slots = 64 edges x {src,dst}
    const int slot    = tid >> 2;     // 0..127
    const int part    = tid & 3;      // 32 floats each
    const int g_e     = slot >> 1;    // edge within tile
    const int g_which = slot & 1;     // 0 = src half (k<128), 1 = dst half

    for (int t = blockIdx.x; t < NT; t += gridDim.x) {
        // ---------------- gather: h[src], h[dst] -> f16 -> Alds ----------------
        {
            int eg = t * TE + g_e;
            if (eg >= N_EDGES) eg = N_EDGES - 1;            // clamp tail (writes guarded later)
            const int node = g_which ? dst[eg] : src[eg];
            const float* p = h + node * F + part * 32;
            const int kbase = g_which * 128 + part * 32;
            #pragma unroll
            for (int c = 0; c < 4; ++c) {
                float4 v0 = *(const float4*)(p + c * 8);
                float4 v1 = *(const float4*)(p + c * 8 + 4);
                f16x8 x;
                x[0] = (_Float16)v0.x; x[1] = (_Float16)v0.y;
                x[2] = (_Float16)v0.z; x[3] = (_Float16)v0.w;
                x[4] = (_Float16)v1.x; x[5] = (_Float16)v1.y;
                x[6] = (_Float16)v1.z; x[7] = (_Float16)v1.w;
                int byte = g_e * 512 + (kbase + c * 8) * 2;
                byte ^= (g_e & 7) << 4;                     // bank swizzle
                *(f16x8*)(Alds + byte) = x;
            }
        }
        __syncthreads();                                    // A ready

        // ---------------- layer 1: X1 = relu(A @ W1^T + b1) ----------------
        #pragma unroll
        for (int m = 0; m < 4; ++m) {                       // 4 m-tiles of 16 edges
            f32x4 acc = {0.f, 0.f, 0.f, 0.f};
            #pragma unroll
            for (int kt = 0; kt < 8; ++kt) {
                const int edge = m * 16 + l15;
                int byte = edge * 512 + (kt * 32 + lk * 8) * 2;
                byte ^= (edge & 7) << 4;
                f16x8 a = *(const f16x8*)(Alds + byte);     // ds_read_b128
                acc = __builtin_amdgcn_mfma_f32_16x16x32_f16(a, w1f[kt], acc, 0, 0, 0);
            }
            // C layout: col = lane&15 (= n1), row = m*16 + (lane>>4)*4 + r
            #pragma unroll
            for (int r = 0; r < 4; ++r) {
                float v = acc[r] + b1v;
                v = v > 0.f ? v : 0.f;
                const int edge = m * 16 + lk * 4 + r;
                int byte = edge * 256 + n1 * 2;
                byte ^= (edge & 7) << 4;
                *(_Float16*)(Xlds + byte) = (_Float16)v;
            }
        }
        __syncthreads();                                    // X1 ready

        // ---------------- layer 2: X2 = relu(X1 @ W2^T + b2) ----------------
        f32x4 acc2[4];
        #pragma unroll
        for (int m = 0; m < 4; ++m) {
            f32x4 acc = {0.f, 0.f, 0.f, 0.f};
            #pragma unroll
            for (int kt = 0; kt < 4; ++kt) {
                const int edge = m * 16 + l15;
                int byte = edge * 256 + (kt * 32 + lk * 8) * 2;
                byte ^= (edge & 7) << 4;
                f16x8 a = *(const f16x8*)(Xlds + byte);
                acc = __builtin_amdgcn_mfma_f32_16x16x32_f16(a, w2f[kt], acc, 0, 0, 0);
            }
            acc2[m] = acc;
        }
        __syncthreads();                                    // all X1 reads done -> can overwrite
        #pragma unroll
        for (int m = 0; m < 4; ++m) {
            #pragma unroll
            for (int r = 0; r < 4; ++r) {
                float v = acc2[m][r] + b2v;
                v = v > 0.f ? v : 0.f;
                const int edge = m * 16 + lk * 4 + r;
                int byte = edge * 256 + n1 * 2;
                byte ^= (edge & 7) << 4;
                *(_Float16*)(Xlds + byte) = (_Float16)v;    // X2 into same buffer
            }
        }
        __syncthreads();                                    // X2 ready

        // ---------------- layer 3: score = X2 @ W3^T + b3 ----------------
        {
            const int e_loc = tid >> 3;                     // 0..63
            const int cgrp  = tid & 7;                      // 16 cols each
            const int swz   = (e_loc & 7) << 4;
            const int base  = e_loc * 256 + cgrp * 32;
            f16x8 x0 = *(const f16x8*)(Xlds + (base ^ swz));
            f16x8 x1 = *(const f16x8*)(Xlds + ((base + 16) ^ swz));
            float p = 0.f;
            #pragma unroll
            for (int i = 0; i < 8; ++i) p += (float)x0[i] * w3r[i];
            #pragma unroll
            for (int i = 0; i < 8; ++i) p += (float)x1[i] * w3r[8 + i];
            p += __shfl_xor(p, 1);
            p += __shfl_xor(p, 2);
            p += __shfl_xor(p, 4);
            const int eg = t * TE + e_loc;
            if (cgrp == 0 && eg < N_EDGES) out[eg] = p + b3v;
        }
        // no trailing barrier needed: next iter writes only Alds before the
        // post-gather barrier, and Xlds is first written after that barrier.
    }
}

extern "C" void kernel_launch(void* const* d_in, const int* in_sizes, int n_in,
                              void* d_out, int out_size, void* d_ws, size_t ws_size,
                              hipStream_t stream) {
    const float* h   = (const float*)d_in[0];
    const int*   src = (const int*)  d_in[1];
    const int*   dst = (const int*)  d_in[2];
    const float* W1  = (const float*)d_in[3];
    const float* b1  = (const float*)d_in[4];
    const float* W2  = (const float*)d_in[5];
    const float* b2  = (const float*)d_in[6];
    const float* W3  = (const float*)d_in[7];
    const float* b3  = (const float*)d_in[8];
    float* out = (float*)d_out;

    edge_mlp_kernel<<<GRID, BLOCK, 0, stream>>>(h, src, dst, W1, b1, W2, b2, W3, b3, out);
}

// Round 4
// 211.795 us; speedup vs baseline: 1.1822x; 1.1822x over previous
//
#include <hip/hip_runtime.h>
#include <hip/hip_bf16.h>
#include <hip/hip_fp16.h>

// Edge-MLP: score[e] = W3·relu(W2·relu(W1u·h[src[e]] + W1v·h[dst[e]] + b1) + b2) + b3
// R4 (= audited R3): h pre-converted to f16 in d_ws (halves gather bytes); A-tile
// double-buffered, filled with async global_load_lds (16B). Mid-tile barriers are
// raw s_barrier with lgkmcnt-only drains so the next-tile gather DMA stays in
// flight across the whole compute phase (one vmcnt(0) per tile at loop head).

#define N_NODES 100000
#define N_EDGES 500000
#define F       128            // IN_FEATS
#define HID     128
#define TE      64             // edges per tile
#define NT      ((N_EDGES + TE - 1) / TE)   // 7813 tiles
#define GRID    512
#define BLOCK   512            // 8 waves

typedef _Float16 f16x8 __attribute__((ext_vector_type(8)));
typedef float    f32x4 __attribute__((ext_vector_type(4)));

typedef __attribute__((address_space(3))) unsigned int  lds_u32;
typedef __attribute__((address_space(1))) const unsigned int glb_u32;

__device__ __forceinline__ void load_lds16(const void* g, void* l) {
    // async global->LDS DMA: per-lane global src, wave-uniform LDS base + lane*16
    __builtin_amdgcn_global_load_lds((glb_u32*)g, (lds_u32*)l, 16, 0, 0);
}

// barrier with LDS-drain only: does NOT drain vmcnt -> gather DMA stays in flight
__device__ __forceinline__ void bar_lgkm() {
    asm volatile("s_waitcnt lgkmcnt(0)" ::: "memory");
    __builtin_amdgcn_s_barrier();
    __builtin_amdgcn_sched_barrier(0);
}
// full drain barrier: own DMA + idx loads landed, then workgroup sync
__device__ __forceinline__ void bar_vm() {
    asm volatile("s_waitcnt vmcnt(0) lgkmcnt(0)" ::: "memory");
    __builtin_amdgcn_s_barrier();
    __builtin_amdgcn_sched_barrier(0);
}

// ---------------- h -> f16 conversion pass ----------------
__global__ __launch_bounds__(256) void h_to_f16(const float* __restrict__ h,
                                                _Float16* __restrict__ h16) {
    const int i = (blockIdx.x * 256 + threadIdx.x) * 8;   // 12.8M elems, exact
    float4 a = *(const float4*)(h + i);
    float4 b = *(const float4*)(h + i + 4);
    f16x8 v;
    v[0] = (_Float16)a.x; v[1] = (_Float16)a.y; v[2] = (_Float16)a.z; v[3] = (_Float16)a.w;
    v[4] = (_Float16)b.x; v[5] = (_Float16)b.y; v[6] = (_Float16)b.z; v[7] = (_Float16)b.w;
    *(f16x8*)(h16 + i) = v;
}

// ---------------- fused edge kernel (f16 h + async double-buffer) ----------------
__global__ __launch_bounds__(BLOCK) void edge_mlp_v2(
    const _Float16* __restrict__ h16,
    const int*   __restrict__ src,
    const int*   __restrict__ dst,
    const float* __restrict__ W1,   // [128][256]
    const float* __restrict__ b1,
    const float* __restrict__ W2,   // [128][128]
    const float* __restrict__ b2,
    const float* __restrict__ W3,   // [1][128]
    const float* __restrict__ b3,
    float*       __restrict__ out)
{
    // A tiles: 2 x [64 edges][256 k] f16, XOR-swizzled (byte ^= (edge&7)<<4). 2x32KB.
    __shared__ __align__(128) char Alds[2 * TE * 512];
    // X tile: [64 edges][128 cols] f16, swizzled. X1 then X2. 16KB. (80KB -> 2 blk/CU)
    __shared__ __align__(128) char Xlds[TE * 256];

    const int tid  = threadIdx.x;
    const int wave = tid >> 6;
    const int lane = tid & 63;
    const int l15  = lane & 15;
    const int lk   = lane >> 4;       // 0..3

    // ---- per-block weight fragments (f32 -> f16 regs), wave owns 16 output cols ----
    const int n1 = wave * 16 + l15;

    f16x8 w1f[8];
    #pragma unroll
    for (int kt = 0; kt < 8; ++kt) {
        const float* p = W1 + n1 * 256 + kt * 32 + lk * 8;
        f16x8 v;
        #pragma unroll
        for (int j = 0; j < 8; ++j) v[j] = (_Float16)p[j];
        w1f[kt] = v;
    }
    const float b1v = b1[n1];

    f16x8 w2f[4];
    #pragma unroll
    for (int kt = 0; kt < 4; ++kt) {
        const float* p = W2 + n1 * 128 + kt * 32 + lk * 8;
        f16x8 v;
        #pragma unroll
        for (int j = 0; j < 8; ++j) v[j] = (_Float16)p[j];
        w2f[kt] = v;
    }
    const float b2v = b2[n1];

    float w3r[16];
    {
        const float* p = W3 + (tid & 7) * 16;
        #pragma unroll
        for (int i = 0; i < 16; ++i) w3r[i] = p[i];
    }
    const float b3v = b3[0];

    // ---- gather geometry ----
    // DMA instr i (= wave*4+j), lane l writes LDS byte i*1024 + l*16.
    //   e     = 2*i + (l>>5)          (row bits p>>9 untouched by XOR mask)
    //   which = (l>>4)&1              (0=src half k<128, 1=dst half; XOR keeps bit4)
    //   k16   = (l&15) ^ (e&7)        (inverse swizzle applied on the SOURCE)
    // -> linear LDS then holds exactly what the swizzled ds_read_b128s expect.
    int eloc[4], k16v[4];
    #pragma unroll
    for (int j = 0; j < 4; ++j) {
        const int i = wave * 4 + j;
        eloc[j] = 2 * i + (lane >> 5);
        k16v[j] = (l15) ^ (eloc[j] & 7);
    }
    const int whichv = (lane >> 4) & 1;
    const int* idxp  = whichv ? dst : src;

    const int t0 = blockIdx.x;

    int nodeCur[4], nodeNext[4];

    // ---- prologue: gather tile t0 into buf0, preload indices for t0+GRID ----
    #pragma unroll
    for (int j = 0; j < 4; ++j) {
        int eg = t0 * TE + eloc[j];
        if (eg >= N_EDGES) eg = N_EDGES - 1;
        nodeCur[j] = idxp[eg];
    }
    #pragma unroll
    for (int j = 0; j < 4; ++j) {
        const _Float16* g = h16 + (size_t)nodeCur[j] * F + k16v[j] * 8;
        load_lds16(g, Alds + (wave * 4 + j) * 1024);
    }
    {
        int tn = t0 + GRID; if (tn > NT - 1) tn = NT - 1;
        #pragma unroll
        for (int j = 0; j < 4; ++j) {
            int eg = tn * TE + eloc[j];
            if (eg >= N_EDGES) eg = N_EDGES - 1;
            nodeNext[j] = idxp[eg];
        }
    }

    int cur = 0;
    for (int t = t0; t < NT; t += GRID) {
        bar_vm();                                           // own DMA landed; all waves synced

        // issue next tile's gather into the other buffer (stays in flight through
        // the whole compute below -- no mid barrier drains vmcnt)
        #pragma unroll
        for (int j = 0; j < 4; ++j) nodeCur[j] = nodeNext[j];
        {
            char* nb = Alds + (cur ^ 1) * (TE * 512);
            #pragma unroll
            for (int j = 0; j < 4; ++j) {
                const _Float16* g = h16 + (size_t)nodeCur[j] * F + k16v[j] * 8;
                load_lds16(g, nb + (wave * 4 + j) * 1024);
            }
        }
        // preload indices two tiles ahead
        {
            int tn2 = t + 2 * GRID; if (tn2 > NT - 1) tn2 = NT - 1;
            #pragma unroll
            for (int j = 0; j < 4; ++j) {
                int eg = tn2 * TE + eloc[j];
                if (eg >= N_EDGES) eg = N_EDGES - 1;
                nodeNext[j] = idxp[eg];
            }
        }

        const char* Ab = Alds + cur * (TE * 512);

        // ---------------- layer 1: X1 = relu(A @ W1^T + b1) ----------------
        #pragma unroll
        for (int m = 0; m < 4; ++m) {
            f32x4 acc = {0.f, 0.f, 0.f, 0.f};
            #pragma unroll
            for (int kt = 0; kt < 8; ++kt) {
                const int edge = m * 16 + l15;
                int byte = edge * 512 + (kt * 32 + lk * 8) * 2;
                byte ^= (edge & 7) << 4;
                f16x8 a = *(const f16x8*)(Ab + byte);
                acc = __builtin_amdgcn_mfma_f32_16x16x32_f16(a, w1f[kt], acc, 0, 0, 0);
            }
            #pragma unroll
            for (int r = 0; r < 4; ++r) {
                float v = acc[r] + b1v;
                v = v > 0.f ? v : 0.f;
                const int edge = m * 16 + lk * 4 + r;
                int byte = edge * 256 + n1 * 2;
                byte ^= (edge & 7) << 4;
                *(_Float16*)(Xlds + byte) = (_Float16)v;
            }
        }
        bar_lgkm();                                         // X1 writes visible; A reads done

        // ---------------- layer 2: X2 = relu(X1 @ W2^T + b2) ----------------
        f32x4 acc2[4];
        #pragma unroll
        for (int m = 0; m < 4; ++m) {
            f32x4 acc = {0.f, 0.f, 0.f, 0.f};
            #pragma unroll
            for (int kt = 0; kt < 4; ++kt) {
                const int edge = m * 16 + l15;
                int byte = edge * 256 + (kt * 32 + lk * 8) * 2;
                byte ^= (edge & 7) << 4;
                f16x8 a = *(const f16x8*)(Xlds + byte);
                acc = __builtin_amdgcn_mfma_f32_16x16x32_f16(a, w2f[kt], acc, 0, 0, 0);
            }
            acc2[m] = acc;
        }
        bar_lgkm();                                         // X1 reads done -> may overwrite
        #pragma unroll
        for (int m = 0; m < 4; ++m) {
            #pragma unroll
            for (int r = 0; r < 4; ++r) {
                float v = acc2[m][r] + b2v;
                v = v > 0.f ? v : 0.f;
                const int edge = m * 16 + lk * 4 + r;
                int byte = edge * 256 + n1 * 2;
                byte ^= (edge & 7) << 4;
                *(_Float16*)(Xlds + byte) = (_Float16)v;    // X2 into same buffer
            }
        }
        bar_lgkm();                                         // X2 ready

        // ---------------- layer 3: score = X2 @ W3^T + b3 ----------------
        {
            const int e_loc = tid >> 3;
            const int cgrp  = tid & 7;
            const int swz   = (e_loc & 7) << 4;
            const int base  = e_loc * 256 + cgrp * 32;
            f16x8 x0 = *(const f16x8*)(Xlds + (base ^ swz));
            f16x8 x1 = *(const f16x8*)(Xlds + ((base + 16) ^ swz));
            float p = 0.f;
            #pragma unroll
            for (int i = 0; i < 8; ++i) p += (float)x0[i] * w3r[i];
            #pragma unroll
            for (int i = 0; i < 8; ++i) p += (float)x1[i] * w3r[8 + i];
            p += __shfl_xor(p, 1);
            p += __shfl_xor(p, 2);
            p += __shfl_xor(p, 4);
            const int eg = t * TE + e_loc;
            if (cgrp == 0 && eg < N_EDGES) out[eg] = p + b3v;
        }
        cur ^= 1;
        // next iter's bar_vm gates buffer reuse (Xlds rewrite + A-buf DMA target)
    }
}

// ---------------- fallback (round-1 kernel: f32 gather, no overlap) ----------------
__global__ __launch_bounds__(BLOCK) void edge_mlp_v1(
    const float* __restrict__ h,
    const int*   __restrict__ src,
    const int*   __restrict__ dst,
    const float* __restrict__ W1,
    const float* __restrict__ b1,
    const float* __restrict__ W2,
    const float* __restrict__ b2,
    const float* __restrict__ W3,
    const float* __restrict__ b3,
    float*       __restrict__ out)
{
    __shared__ __align__(128) char Alds[TE * 512];
    __shared__ __align__(128) char Xlds[TE * 256];

    const int tid  = threadIdx.x;
    const int wave = tid >> 6;
    const int lane = tid & 63;
    const int l15  = lane & 15;
    const int lk   = lane >> 4;

    const int n1 = wave * 16 + l15;

    f16x8 w1f[8];
    #pragma unroll
    for (int kt = 0; kt < 8; ++kt) {
        const float* p = W1 + n1 * 256 + kt * 32 + lk * 8;
        f16x8 v;
        #pragma unroll
        for (int j = 0; j < 8; ++j) v[j] = (_Float16)p[j];
        w1f[kt] = v;
    }
    const float b1v = b1[n1];

    f16x8 w2f[4];
    #pragma unroll
    for (int kt = 0; kt < 4; ++kt) {
        const float* p = W2 + n1 * 128 + kt * 32 + lk * 8;
        f16x8 v;
        #pragma unroll
        for (int j = 0; j < 8; ++j) v[j] = (_Float16)p[j];
        w2f[kt] = v;
    }
    const float b2v = b2[n1];

    float w3r[16];
    {
        const float* p = W3 + (tid & 7) * 16;
        #pragma unroll
        for (int i = 0; i < 16; ++i) w3r[i] = p[i];
    }
    const float b3v = b3[0];

    const int slot    = tid >> 2;
    const int part    = tid & 3;
    const int g_e     = slot >> 1;
    const int g_which = slot & 1;

    for (int t = blockIdx.x; t < NT; t += gridDim.x) {
        {
            int eg = t * TE + g_e;
            if (eg >= N_EDGES) eg = N_EDGES - 1;
            const int node = g_which ? dst[eg] : src[eg];
            const float* p = h + node * F + part * 32;
            const int kbase = g_which * 128 + part * 32;
            #pragma unroll
            for (int c = 0; c < 4; ++c) {
                float4 v0 = *(const float4*)(p + c * 8);
                float4 v1 = *(const float4*)(p + c * 8 + 4);
                f16x8 x;
                x[0] = (_Float16)v0.x; x[1] = (_Float16)v0.y;
                x[2] = (_Float16)v0.z; x[3] = (_Float16)v0.w;
                x[4] = (_Float16)v1.x; x[5] = (_Float16)v1.y;
                x[6] = (_Float16)v1.z; x[7] = (_Float16)v1.w;
                int byte = g_e * 512 + (kbase + c * 8) * 2;
                byte ^= (g_e & 7) << 4;
                *(f16x8*)(Alds + byte) = x;
            }
        }
        __syncthreads();

        #pragma unroll
        for (int m = 0; m < 4; ++m) {
            f32x4 acc = {0.f, 0.f, 0.f, 0.f};
            #pragma unroll
            for (int kt = 0; kt < 8; ++kt) {
                const int edge = m * 16 + l15;
                int byte = edge * 512 + (kt * 32 + lk * 8) * 2;
                byte ^= (edge & 7) << 4;
                f16x8 a = *(const f16x8*)(Alds + byte);
                acc = __builtin_amdgcn_mfma_f32_16x16x32_f16(a, w1f[kt], acc, 0, 0, 0);
            }
            #pragma unroll
            for (int r = 0; r < 4; ++r) {
                float v = acc[r] + b1v;
                v = v > 0.f ? v : 0.f;
                const int edge = m * 16 + lk * 4 + r;
                int byte = edge * 256 + n1 * 2;
                byte ^= (edge & 7) << 4;
                *(_Float16*)(Xlds + byte) = (_Float16)v;
            }
        }
        __syncthreads();

        f32x4 acc2[4];
        #pragma unroll
        for (int m = 0; m < 4; ++m) {
            f32x4 acc = {0.f, 0.f, 0.f, 0.f};
            #pragma unroll
            for (int kt = 0; kt < 4; ++kt) {
                const int edge = m * 16 + l15;
                int byte = edge * 256 + (kt * 32 + lk * 8) * 2;
                byte ^= (edge & 7) << 4;
                f16x8 a = *(const f16x8*)(Xlds + byte);
                acc = __builtin_amdgcn_mfma_f32_16x16x32_f16(a, w2f[kt], acc, 0, 0, 0);
            }
            acc2[m] = acc;
        }
        __syncthreads();
        #pragma unroll
        for (int m = 0; m < 4; ++m) {
            #pragma unroll
            for (int r = 0; r < 4; ++r) {
                float v = acc2[m][r] + b2v;
                v = v > 0.f ? v : 0.f;
                const int edge = m * 16 + lk * 4 + r;
                int byte = edge * 256 + n1 * 2;
                byte ^= (edge & 7) << 4;
                *(_Float16*)(Xlds + byte) = (_Float16)v;
            }
        }
        __syncthreads();

        {
            const int e_loc = tid >> 3;
            const int cgrp  = tid & 7;
            const int swz   = (e_loc & 7) << 4;
            const int base  = e_loc * 256 + cgrp * 32;
            f16x8 x0 = *(const f16x8*)(Xlds + (base ^ swz));
            f16x8 x1 = *(const f16x8*)(Xlds + ((base + 16) ^ swz));
            float p = 0.f;
            #pragma unroll
            for (int i = 0; i < 8; ++i) p += (float)x0[i] * w3r[i];
            #pragma unroll
            for (int i = 0; i < 8; ++i) p += (float)x1[i] * w3r[8 + i];
            p += __shfl_xor(p, 1);
            p += __shfl_xor(p, 2);
            p += __shfl_xor(p, 4);
            const int eg = t * TE + e_loc;
            if (cgrp == 0 && eg < N_EDGES) out[eg] = p + b3v;
        }
    }
}

extern "C" void kernel_launch(void* const* d_in, const int* in_sizes, int n_in,
                              void* d_out, int out_size, void* d_ws, size_t ws_size,
                              hipStream_t stream) {
    const float* h   = (const float*)d_in[0];
    const int*   src = (const int*)  d_in[1];
    const int*   dst = (const int*)  d_in[2];
    const float* W1  = (const float*)d_in[3];
    const float* b1  = (const float*)d_in[4];
    const float* W2  = (const float*)d_in[5];
    const float* b2  = (const float*)d_in[6];
    const float* W3  = (const float*)d_in[7];
    const float* b3  = (const float*)d_in[8];
    float* out = (float*)d_out;

    const size_t need = (size_t)N_NODES * F * sizeof(_Float16);   // 25.6 MB
    if (ws_size >= need) {
        _Float16* h16 = (_Float16*)d_ws;
        h_to_f16<<<6250, 256, 0, stream>>>(h, h16);
        edge_mlp_v2<<<GRID, BLOCK, 0, stream>>>(h16, src, dst, W1, b1, W2, b2, W3, b3, out);
    } else {
        edge_mlp_v1<<<GRID, BLOCK, 0, stream>>>(h, src, dst, W1, b1, W2, b2, W3, b3, out);
    }
}

// Round 7
// 184.643 us; speedup vs baseline: 1.3561x; 1.1470x over previous
//
#include <hip/hip_runtime.h>
#include <hip/hip_bf16.h>
#include <hip/hip_fp16.h>

// Edge-MLP: score[e] = W3·relu(W2·relu(W1u·h[src[e]] + W1v·h[dst[e]] + b1) + b2) + b3
// R7 (= audited R5/R6, unchanged): 32x32x16 MFMA, operand-swapped (W = A-operand,
// edges = N). Each wave owns a 32-hid x 32-edge output block; W1/W2 slices live in
// registers; layer-3 is a lane-local dot (X2 never hits LDS). LDS ops per tile
// ~2.5x fewer than R4. Gather: f16 h in d_ws, async global_load_lds DMA,
// double-buffered, lgkm-only mid barriers (DMA in flight across whole compute).

#define N_NODES 100000
#define N_EDGES 500000
#define F       128
#define HID     128
#define TE      64
#define NT      ((N_EDGES + TE - 1) / TE)   // 7813
#define GRID    256
#define BLOCK   512                          // 8 waves = 4 mh x 2 ne

typedef _Float16 f16x8  __attribute__((ext_vector_type(8)));
typedef float    f32x16 __attribute__((ext_vector_type(16)));

typedef __attribute__((address_space(3))) unsigned int  lds_u32;
typedef __attribute__((address_space(1))) const unsigned int glb_u32;

__device__ __forceinline__ void load_lds16(const void* g, void* l) {
    __builtin_amdgcn_global_load_lds((glb_u32*)g, (lds_u32*)l, 16, 0, 0);
}
__device__ __forceinline__ void bar_lgkm() {
    asm volatile("s_waitcnt lgkmcnt(0)" ::: "memory");
    __builtin_amdgcn_s_barrier();
    __builtin_amdgcn_sched_barrier(0);
}
__device__ __forceinline__ void bar_vm() {
    asm volatile("s_waitcnt vmcnt(0) lgkmcnt(0)" ::: "memory");
    __builtin_amdgcn_s_barrier();
    __builtin_amdgcn_sched_barrier(0);
}

// ---------------- h -> f16 conversion pass ----------------
__global__ __launch_bounds__(256) void h_to_f16(const float* __restrict__ h,
                                                _Float16* __restrict__ h16) {
    const int i = (blockIdx.x * 256 + threadIdx.x) * 8;   // 12.8M elems exact
    float4 a = *(const float4*)(h + i);
    float4 b = *(const float4*)(h + i + 4);
    f16x8 v;
    v[0] = (_Float16)a.x; v[1] = (_Float16)a.y; v[2] = (_Float16)a.z; v[3] = (_Float16)a.w;
    v[4] = (_Float16)b.x; v[5] = (_Float16)b.y; v[6] = (_Float16)b.z; v[7] = (_Float16)b.w;
    *(f16x8*)(h16 + i) = v;
}

// ---------------- fused edge kernel, v3 ----------------
__global__ __launch_bounds__(BLOCK, 2) void edge_mlp_v3(
    const _Float16* __restrict__ h16,
    const int*   __restrict__ src,
    const int*   __restrict__ dst,
    const float* __restrict__ W1,   // [128][256]
    const float* __restrict__ b1,
    const float* __restrict__ W2,   // [128][128]
    const float* __restrict__ b2,
    const float* __restrict__ W3,   // [1][128]
    const float* __restrict__ b3,
    float*       __restrict__ out)
{
    // A tiles: 2 x [64 e][256 k] f16, swizzle byte^=((e&15)<<4). 2x32KB.
    __shared__ __align__(128) char Alds[2 * TE * 512];
    // X tile: [64 e][128 hid] f16, same swizzle. 16KB.
    __shared__ __align__(128) char Xlds[TE * 256];
    // layer-3 partials: [wave(=mh*2+ne)][edge-col]
    __shared__ float Spart[8][32];

    const int tid  = threadIdx.x;
    const int wave = tid >> 6;
    const int lane = tid & 63;
    const int mh   = wave >> 1;       // hid block 0..3
    const int ne   = wave & 1;        // edge block 0..1
    const int col  = lane & 31;       // W row within mh block / edge col within ne block
    const int h    = lane >> 5;       // k-half

    // ---- weight slices into registers ----
    // A-operand layout (32x32x16 f16): lane holds A[row=lane&31][k=8*(lane>>5)+j]
    f16x8 w1a[16];
    #pragma unroll
    for (int kt = 0; kt < 16; ++kt) {
        const float* p = W1 + (mh * 32 + col) * 256 + kt * 16 + 8 * h;
        f16x8 v;
        #pragma unroll
        for (int j = 0; j < 8; ++j) v[j] = (_Float16)p[j];
        w1a[kt] = v;
    }
    f16x8 w2a[8];
    #pragma unroll
    for (int kt = 0; kt < 8; ++kt) {
        const float* p = W2 + (mh * 32 + col) * 128 + kt * 16 + 8 * h;
        f16x8 v;
        #pragma unroll
        for (int j = 0; j < 8; ++j) v[j] = (_Float16)p[j];
        w2a[kt] = v;
    }
    // per-lane row tables for C-layout rows: row(r) = mh*32 + (r&3) + 8*(r>>2) + 4h
    float b1pl[16], b2pl[16], w3pl[16];
    #pragma unroll
    for (int r = 0; r < 16; ++r) {
        const int row = mh * 32 + (r & 3) + 8 * (r >> 2) + 4 * h;
        b1pl[r] = b1[row];
        b2pl[r] = b2[row];
        w3pl[r] = W3[row];
    }
    const float b3v = b3[0];

    // ---- gather geometry (DMA instr i = wave*4+j; lane l -> LDS byte i*1024+l*16)
    //   physical: row e = 2i + (l>>5), in-row chunk = l&31
    //   logical chunk = (l&31) ^ (e&15): bit4 (src/dst) untouched by XOR ->
    //   which = (l>>4)&1; within-half chunk k16 = (l&15) ^ (e&15)
    int eloc[4], k16v[4];
    #pragma unroll
    for (int j = 0; j < 4; ++j) {
        const int i = wave * 4 + j;
        eloc[j] = 2 * i + h;
        k16v[j] = (lane & 15) ^ (eloc[j] & 15);
    }
    const int whichv = (lane >> 4) & 1;
    const int* idxp  = whichv ? dst : src;

    const int t0 = blockIdx.x;
    int nodeCur[4], nodeNext[4];

    #pragma unroll
    for (int j = 0; j < 4; ++j) {
        int eg = t0 * TE + eloc[j];
        if (eg >= N_EDGES) eg = N_EDGES - 1;
        nodeCur[j] = idxp[eg];
    }
    #pragma unroll
    for (int j = 0; j < 4; ++j) {
        const _Float16* g = h16 + (size_t)nodeCur[j] * F + k16v[j] * 8;
        load_lds16(g, Alds + (wave * 4 + j) * 1024);
    }
    {
        int tn = t0 + GRID; if (tn > NT - 1) tn = NT - 1;
        #pragma unroll
        for (int j = 0; j < 4; ++j) {
            int eg = tn * TE + eloc[j];
            if (eg >= N_EDGES) eg = N_EDGES - 1;
            nodeNext[j] = idxp[eg];
        }
    }

    const int e_own = ne * 32 + col;                 // this lane's edge column
    const int exor  = (e_own & 15) << 4;

    int cur = 0;
    for (int t = t0; t < NT; t += GRID) {
        bar_vm();                                    // this tile's DMA landed everywhere

        // issue next tile's gather (in flight across whole compute)
        #pragma unroll
        for (int j = 0; j < 4; ++j) nodeCur[j] = nodeNext[j];
        {
            char* nb = Alds + (cur ^ 1) * (TE * 512);
            #pragma unroll
            for (int j = 0; j < 4; ++j) {
                const _Float16* g = h16 + (size_t)nodeCur[j] * F + k16v[j] * 8;
                load_lds16(g, nb + (wave * 4 + j) * 1024);
            }
        }
        {
            int tn2 = t + 2 * GRID; if (tn2 > NT - 1) tn2 = NT - 1;
            #pragma unroll
            for (int j = 0; j < 4; ++j) {
                int eg = tn2 * TE + eloc[j];
                if (eg >= N_EDGES) eg = N_EDGES - 1;
                nodeNext[j] = idxp[eg];
            }
        }

        const char* Ab = Alds + cur * (TE * 512);

        // ---------------- layer 1: X1^T[mh-block][e] = relu(W1 A^T + b1) ----------
        f32x16 acc1 = {};
        #pragma unroll
        for (int kt = 0; kt < 16; ++kt) {
            // B-frag: lane holds In[e_own][k = kt*16 + 8h .. +8]
            const int c = (kt * 32 + 16 * h) ^ exor;
            f16x8 bf = *(const f16x8*)(Ab + e_own * 512 + c);
            acc1 = __builtin_amdgcn_mfma_f32_32x32x16_f16(w1a[kt], bf, acc1, 0, 0, 0);
        }
        // epilogue: bias+relu, pack row pairs, write X1[e][hid]
        #pragma unroll
        for (int pr = 0; pr < 8; ++pr) {
            float v0 = acc1[2 * pr]     + b1pl[2 * pr];
            float v1 = acc1[2 * pr + 1] + b1pl[2 * pr + 1];
            v0 = v0 > 0.f ? v0 : 0.f;
            v1 = v1 > 0.f ? v1 : 0.f;
            union { _Float16 q[2]; unsigned u; } pk;
            pk.q[0] = (_Float16)v0; pk.q[1] = (_Float16)v1;
            const int row0 = mh * 32 + ((2 * pr) & 3) + 8 * (pr >> 1) + 4 * h;
            const int c = (row0 * 2) ^ exor;
            *(unsigned*)(Xlds + e_own * 256 + c) = pk.u;
        }
        bar_lgkm();                                  // X1 visible

        // ---------------- layer 2: X2^T[mh-block][e] (stays in registers) --------
        f32x16 acc2 = {};
        #pragma unroll
        for (int kt = 0; kt < 8; ++kt) {
            const int c = (kt * 32 + 16 * h) ^ exor;
            f16x8 xf = *(const f16x8*)(Xlds + e_own * 256 + c);
            acc2 = __builtin_amdgcn_mfma_f32_32x32x16_f16(w2a[kt], xf, acc2, 0, 0, 0);
        }

        // ---------------- layer 3: lane-local dot over this wave's 32 hid rows ----
        float p = 0.f;
        #pragma unroll
        for (int r = 0; r < 16; ++r) {
            float v = acc2[r] + b2pl[r];
            v = v > 0.f ? v : 0.f;
            p = fmaf(w3pl[r], v, p);
        }
        p += __shfl_xor(p, 32);                      // both k-halves -> full 32 rows
        if (lane < 32) Spart[wave][lane] = p;
        bar_lgkm();                                  // Spart visible

        // reduce 4 mh partials per edge + store
        if (tid < TE) {
            const int eg = t * TE + tid;
            const int w0 = tid >> 5, c0 = tid & 31;
            float s = Spart[w0][c0] + Spart[2 + w0][c0]
                    + Spart[4 + w0][c0] + Spart[6 + w0][c0] + b3v;
            if (eg < N_EDGES) out[eg] = s;
        }
        cur ^= 1;
        // next bar_vm gates A-buf reuse and Spart rewrite
    }
}

// ---------------- fallback (round-1 proven kernel) ----------------
__global__ __launch_bounds__(512) void edge_mlp_v1(
    const float* __restrict__ h,
    const int*   __restrict__ src,
    const int*   __restrict__ dst,
    const float* __restrict__ W1,
    const float* __restrict__ b1,
    const float* __restrict__ W2,
    const float* __restrict__ b2,
    const float* __restrict__ W3,
    const float* __restrict__ b3,
    float*       __restrict__ out)
{
    __shared__ __align__(128) char Alds[TE * 512];
    __shared__ __align__(128) char Xlds[TE * 256];
    typedef float f32x4 __attribute__((ext_vector_type(4)));

    const int tid  = threadIdx.x;
    const int wave = tid >> 6;
    const int lane = tid & 63;
    const int l15  = lane & 15;
    const int lk   = lane >> 4;
    const int n1 = wave * 16 + l15;

    f16x8 w1f[8];
    #pragma unroll
    for (int kt = 0; kt < 8; ++kt) {
        const float* p = W1 + n1 * 256 + kt * 32 + lk * 8;
        f16x8 v;
        #pragma unroll
        for (int j = 0; j < 8; ++j) v[j] = (_Float16)p[j];
        w1f[kt] = v;
    }
    const float b1v = b1[n1];
    f16x8 w2f[4];
    #pragma unroll
    for (int kt = 0; kt < 4; ++kt) {
        const float* p = W2 + n1 * 128 + kt * 32 + lk * 8;
        f16x8 v;
        #pragma unroll
        for (int j = 0; j < 8; ++j) v[j] = (_Float16)p[j];
        w2f[kt] = v;
    }
    const float b2v = b2[n1];
    float w3r[16];
    {
        const float* p = W3 + (tid & 7) * 16;
        #pragma unroll
        for (int i = 0; i < 16; ++i) w3r[i] = p[i];
    }
    const float b3v = b3[0];

    const int slot = tid >> 2, part = tid & 3;
    const int g_e = slot >> 1, g_which = slot & 1;

    for (int t = blockIdx.x; t < NT; t += gridDim.x) {
        {
            int eg = t * TE + g_e;
            if (eg >= N_EDGES) eg = N_EDGES - 1;
            const int node = g_which ? dst[eg] : src[eg];
            const float* p = h + node * F + part * 32;
            const int kbase = g_which * 128 + part * 32;
            #pragma unroll
            for (int c = 0; c < 4; ++c) {
                float4 v0 = *(const float4*)(p + c * 8);
                float4 v1 = *(const float4*)(p + c * 8 + 4);
                f16x8 x;
                x[0] = (_Float16)v0.x; x[1] = (_Float16)v0.y;
                x[2] = (_Float16)v0.z; x[3] = (_Float16)v0.w;
                x[4] = (_Float16)v1.x; x[5] = (_Float16)v1.y;
                x[6] = (_Float16)v1.z; x[7] = (_Float16)v1.w;
                int byte = g_e * 512 + (kbase + c * 8) * 2;
                byte ^= (g_e & 7) << 4;
                *(f16x8*)(Alds + byte) = x;
            }
        }
        __syncthreads();
        #pragma unroll
        for (int m = 0; m < 4; ++m) {
            f32x4 acc = {0.f, 0.f, 0.f, 0.f};
            #pragma unroll
            for (int kt = 0; kt < 8; ++kt) {
                const int edge = m * 16 + l15;
                int byte = edge * 512 + (kt * 32 + lk * 8) * 2;
                byte ^= (edge & 7) << 4;
                f16x8 a = *(const f16x8*)(Alds + byte);
                acc = __builtin_amdgcn_mfma_f32_16x16x32_f16(a, w1f[kt], acc, 0, 0, 0);
            }
            #pragma unroll
            for (int r = 0; r < 4; ++r) {
                float v = acc[r] + b1v;
                v = v > 0.f ? v : 0.f;
                const int edge = m * 16 + lk * 4 + r;
                int byte = edge * 256 + n1 * 2;
                byte ^= (edge & 7) << 4;
                *(_Float16*)(Xlds + byte) = (_Float16)v;
            }
        }
        __syncthreads();
        f32x4 acc2[4];
        #pragma unroll
        for (int m = 0; m < 4; ++m) {
            f32x4 acc = {0.f, 0.f, 0.f, 0.f};
            #pragma unroll
            for (int kt = 0; kt < 4; ++kt) {
                const int edge = m * 16 + l15;
                int byte = edge * 256 + (kt * 32 + lk * 8) * 2;
                byte ^= (edge & 7) << 4;
                f16x8 a = *(const f16x8*)(Xlds + byte);
                acc = __builtin_amdgcn_mfma_f32_16x16x32_f16(a, w2f[kt], acc, 0, 0, 0);
            }
            acc2[m] = acc;
        }
        __syncthreads();
        #pragma unroll
        for (int m = 0; m < 4; ++m) {
            #pragma unroll
            for (int r = 0; r < 4; ++r) {
                float v = acc2[m][r] + b2v;
                v = v > 0.f ? v : 0.f;
                const int edge = m * 16 + lk * 4 + r;
                int byte = edge * 256 + n1 * 2;
                byte ^= (edge & 7) << 4;
                *(_Float16*)(Xlds + byte) = (_Float16)v;
            }
        }
        __syncthreads();
        {
            const int e_loc = tid >> 3;
            const int cgrp  = tid & 7;
            const int swz   = (e_loc & 7) << 4;
            const int base  = e_loc * 256 + cgrp * 32;
            f16x8 x0 = *(const f16x8*)(Xlds + (base ^ swz));
            f16x8 x1 = *(const f16x8*)(Xlds + ((base + 16) ^ swz));
            float p = 0.f;
            #pragma unroll
            for (int i = 0; i < 8; ++i) p += (float)x0[i] * w3r[i];
            #pragma unroll
            for (int i = 0; i < 8; ++i) p += (float)x1[i] * w3r[8 + i];
            p += __shfl_xor(p, 1);
            p += __shfl_xor(p, 2);
            p += __shfl_xor(p, 4);
            const int eg = t * TE + e_loc;
            if (cgrp == 0 && eg < N_EDGES) out[eg] = p + b3v;
        }
    }
}

extern "C" void kernel_launch(void* const* d_in, const int* in_sizes, int n_in,
                              void* d_out, int out_size, void* d_ws, size_t ws_size,
                              hipStream_t stream) {
    const float* h   = (const float*)d_in[0];
    const int*   src = (const int*)  d_in[1];
    const int*   dst = (const int*)  d_in[2];
    const float* W1  = (const float*)d_in[3];
    const float* b1  = (const float*)d_in[4];
    const float* W2  = (const float*)d_in[5];
    const float* b2  = (const float*)d_in[6];
    const float* W3  = (const float*)d_in[7];
    const float* b3  = (const float*)d_in[8];
    float* out = (float*)d_out;

    const size_t need = (size_t)N_NODES * F * sizeof(_Float16);   // 25.6 MB
    if (ws_size >= need) {
        _Float16* h16 = (_Float16*)d_ws;
        h_to_f16<<<6250, 256, 0, stream>>>(h, h16);
        edge_mlp_v3<<<GRID, BLOCK, 0, stream>>>(h16, src, dst, W1, b1, W2, b2, W3, b3, out);
    } else {
        edge_mlp_v1<<<512, 512, 0, stream>>>(h, src, dst, W1, b1, W2, b2, W3, b3, out);
    }
}